// Round 13
// baseline (47.593 us; speedup 1.0000x reference)
//
#include <hip/hip_runtime.h>
#include <cstddef>

// Problem constants (from reference): B=4, N=4096, D=128, R=4, K=16, O=128
namespace {
constexpr int B_ = 4, N_ = 4096, D_ = 128, R_ = 4, K_ = 16, O_ = 128;
constexpr int TN = 64;                 // nodes per block
constexpr int THREADS = 1024;          // 16 waves, 1 block/CU (grid=256)
constexpr int KK = (R_ + 1) * D_;      // 640 stacked-K
constexpr int KR = R_ * D_;            // 512 relation-K (in LDS agg)
constexpr int PITCH_A = KR + 8;        // 520 bf16 per agg row
constexpr int CH = 1024;               // table rows per LDS chunk (128 KB)
constexpr int NCH = N_ / CH;           // 4 chunks
}

typedef __bf16 bf16x8 __attribute__((ext_vector_type(8)));
typedef __bf16 bf16x4 __attribute__((ext_vector_type(4)));
typedef float  f32x4v __attribute__((ext_vector_type(4)));
typedef float  f32x2v __attribute__((ext_vector_type(2)));
using u32 = unsigned int;
using u16 = unsigned short;

// ---- prep (single pass over nf): bf16 + fp8 UNPADDED tables + bf16 W^T ----
// xtb [B][N][D] bf16 (self path), xt8 [B][N][D] fp8 e4m3 (gather path),
// wt [O][KK] with wt[o][kk] = stackedW[kk][o]. idx==0 (pad) handled by a
// zero mask in the gather, so no padded row is needed.
__global__ __launch_bounds__(256)
void prep_all(const float* __restrict__ nf, const float* __restrict__ relk,
              const float* __restrict__ selfk,
              __bf16* __restrict__ xtb, unsigned char* __restrict__ xt8,
              __bf16* __restrict__ wt) {
    int t = blockIdx.x * 256 + threadIdx.x;
    const int total_tab = B_ * N_ * (D_ / 4);           // 4-element chunks
    if (t < total_tab) {
        const float4 v = *(const float4*)(nf + (size_t)t * 4);
        bf16x4 res;
        res[0] = (__bf16)v.x; res[1] = (__bf16)v.y;
        res[2] = (__bf16)v.z; res[3] = (__bf16)v.w;
        *(bf16x4*)(xtb + (size_t)t * 4) = res;
        u32 v8 = (u32)__builtin_amdgcn_cvt_pk_fp8_f32(v.x, v.y, 0, false);
        v8     = (u32)__builtin_amdgcn_cvt_pk_fp8_f32(v.z, v.w, (int)v8, true);
        *(u32*)(xt8 + (size_t)t * 4) = v8;
        return;
    }
    t -= total_tab;
    if (t < O_ * (KK / 4)) {
        const int o   = t / (KK / 4);
        const int kk  = (t % (KK / 4)) * 4;
        bf16x4 res;
        #pragma unroll
        for (int i = 0; i < 4; ++i) {
            const int kki = kk + i;
            const float w = (kki < KR) ? relk[(size_t)kki * O_ + o]
                                       : selfk[(size_t)(kki - KR) * O_ + o];
            res[i] = (__bf16)w;
        }
        *(bf16x4*)(wt + (size_t)o * KK + kk) = res;
    }
}

// ---- main: LDS-chunked gather (random reads hit LDS, not L2) + MFMA ----
__global__ __launch_bounds__(THREADS, 4)
void gcn_fused(const __bf16* __restrict__ xtb,          // [B][N][D] bf16
               const unsigned char* __restrict__ xt8,   // [B][N][D] fp8
               const int*    __restrict__ nbr,          // [B][R][N][K]
               const __bf16* __restrict__ wt,           // [O][KK] bf16
               const float*  __restrict__ bias,         // [O]
               float*        __restrict__ out)          // [B][N][O]
{
    __shared__ u16 sidx[TN][R_][K_];     // 8 KB: per-(n,r) idx sorted by chunk
    __shared__ u32 scnt[TN][R_];         // 1 KB: packed u8 counts per chunk
    __shared__ union ChunkAgg {
        unsigned char chunk[CH * D_];    // 128 KB fp8 table chunk
        __bf16 agg[TN][PITCH_A];         // 66.5 KB (overlays after gather)
    } u;

    // batch<->XCD affinity (r2-verified)
    const int hw  = blockIdx.x;          // 256 blocks, 1 per CU
    const int xcd = hw & 7;
    const int b   = xcd >> 1;
    const int lb  = ((hw >> 3) << 1) | (xcd & 1);    // 0..63 within batch
    const int n0  = lb * TN;

    const int t = threadIdx.x;
    const int w = t >> 6, l = t & 63;
    const int g = l >> 3, s = l & 7;     // gather: group 0..7, 16B-slot 0..7

    // ---- Sort phase: threads 0..255, one per (n,r): counting-sort the 16
    // indices by chunk key ((idx-1)>>10; idx==0 -> key 0, masked later).
    if (t < TN * R_) {
        const int n = t >> 2, r = t & 3;
        const int* ip = nbr + (((size_t)(b * R_ + r) * N_) + n0 + n) * K_;
        int iv[K_];
        {
            const int4 q0 = ((const int4*)ip)[0];
            const int4 q1 = ((const int4*)ip)[1];
            const int4 q2 = ((const int4*)ip)[2];
            const int4 q3 = ((const int4*)ip)[3];
            iv[0]=q0.x; iv[1]=q0.y; iv[2]=q0.z; iv[3]=q0.w;
            iv[4]=q1.x; iv[5]=q1.y; iv[6]=q1.z; iv[7]=q1.w;
            iv[8]=q2.x; iv[9]=q2.y; iv[10]=q2.z; iv[11]=q2.w;
            iv[12]=q3.x; iv[13]=q3.y; iv[14]=q3.z; iv[15]=q3.w;
        }
        int cnt0=0, cnt1=0, cnt2=0, cnt3=0;
        #pragma unroll
        for (int j = 0; j < K_; ++j) {
            const int key = (iv[j] == 0) ? 0 : ((iv[j] - 1) >> 10);
            cnt0 += (key == 0); cnt1 += (key == 1);
            cnt2 += (key == 2); cnt3 += (key == 3);
        }
        int o0 = 0, o1 = cnt0, o2 = cnt0 + cnt1, o3 = cnt0 + cnt1 + cnt2;
        #pragma unroll
        for (int j = 0; j < K_; ++j) {
            const int key = (iv[j] == 0) ? 0 : ((iv[j] - 1) >> 10);
            int pos;
            if (key == 0)      pos = o0++;
            else if (key == 1) pos = o1++;
            else if (key == 2) pos = o2++;
            else               pos = o3++;
            sidx[n][r][pos] = (u16)iv[j];
        }
        scnt[n][r] = (u32)cnt0 | ((u32)cnt1 << 8) | ((u32)cnt2 << 16)
                   | ((u32)cnt3 << 24);
    }
    __syncthreads();

    // ---- Gather: each 8-lane group owns two (n,r) streams; lane slot s
    // covers fp8 elems [s*16, s*16+16) of a row. Accumulate in registers.
    const int p0 = w * 8 + g;            // stream 0: (n,r) = (p>>2, p&3)
    const int p1 = 128 + w * 8 + g;      // stream 1
    const int n0p = p0 >> 2, r0p = p0 & 3;
    const int n1p = p1 >> 2, r1p = p1 & 3;

    f32x2v A0[8], A1[8];
    #pragma unroll
    for (int q = 0; q < 8; ++q) { A0[q] = (f32x2v){0.f, 0.f}; A1[q] = (f32x2v){0.f, 0.f}; }

    const unsigned char* __restrict__ tb8 = xt8 + (size_t)b * N_ * D_;

    #pragma unroll
    for (int c = 0; c < NCH; ++c) {
        // stage chunk c: 1024 threads x 8 x 16B, contiguous (fast VMEM path)
        #pragma unroll
        for (int j = 0; j < 8; ++j) {
            const int flat = j * THREADS + t;
            const uint4 v = *(const uint4*)(tb8 + ((size_t)c * CH * D_) + (size_t)flat * 16);
            *(uint4*)(u.chunk + (size_t)flat * 16) = v;
        }
        __syncthreads();

        #define GCN_STREAM(NP, RP, ACC)                                        \
        {                                                                      \
            const u32 pc = scnt[NP][RP];                                       \
            int off = 0;                                                       \
            for (int cc = 0; cc < c; ++cc) off += (pc >> (8 * cc)) & 0xff;     \
            const int cnt = (pc >> (8 * c)) & 0xff;                            \
            for (int j = 0; j < cnt; ++j) {                                    \
                const int idx = sidx[NP][RP][off + j];  /* group-uniform */    \
                const float m = idx ? 0.0625f : 0.0f;                          \
                int ro = idx - 1 - c * CH; ro = ro < 0 ? 0 : ro;               \
                const uint4 d = *(const uint4*)(u.chunk + ro * D_ + s * 16);   \
                const f32x2v mm = {m, m};                                      \
                ACC[0] += mm * __builtin_amdgcn_cvt_pk_f32_fp8(d.x, false);    \
                ACC[1] += mm * __builtin_amdgcn_cvt_pk_f32_fp8(d.x, true);     \
                ACC[2] += mm * __builtin_amdgcn_cvt_pk_f32_fp8(d.y, false);    \
                ACC[3] += mm * __builtin_amdgcn_cvt_pk_f32_fp8(d.y, true);     \
                ACC[4] += mm * __builtin_amdgcn_cvt_pk_f32_fp8(d.z, false);    \
                ACC[5] += mm * __builtin_amdgcn_cvt_pk_f32_fp8(d.z, true);     \
                ACC[6] += mm * __builtin_amdgcn_cvt_pk_f32_fp8(d.w, false);    \
                ACC[7] += mm * __builtin_amdgcn_cvt_pk_f32_fp8(d.w, true);     \
            }                                                                  \
        }
        GCN_STREAM(n0p, r0p, A0)
        GCN_STREAM(n1p, r1p, A1)
        #undef GCN_STREAM
        __syncthreads();                 // all reads done before restage
    }

    // ---- Write agg (chunk region re-used; loop-end barrier protects it) ----
    {
        bf16x8 r0, r1;
        #pragma unroll
        for (int q = 0; q < 4; ++q) {
            r0[2*q]   = (__bf16)A0[q].x;   r0[2*q+1] = (__bf16)A0[q].y;
            r1[2*q]   = (__bf16)A0[q+4].x; r1[2*q+1] = (__bf16)A0[q+4].y;
        }
        *(bf16x8*)&u.agg[n0p][r0p * D_ + s * 16]     = r0;
        *(bf16x8*)&u.agg[n0p][r0p * D_ + s * 16 + 8] = r1;
        #pragma unroll
        for (int q = 0; q < 4; ++q) {
            r0[2*q]   = (__bf16)A1[q].x;   r0[2*q+1] = (__bf16)A1[q].y;
            r1[2*q]   = (__bf16)A1[q+4].x; r1[2*q+1] = (__bf16)A1[q+4].y;
        }
        *(bf16x8*)&u.agg[n1p][r1p * D_ + s * 16]     = r0;
        *(bf16x8*)&u.agg[n1p][r1p * D_ + s * 16 + 8] = r1;
    }
    __syncthreads();

    // ---- Phase 2: MFMA. Wave w: col-tile ct = w&7, M-half mh = w>>3.
    // Relation-K (512) from LDS agg; self-K (128) + W from global (L2-hit).
    const int lr = l & 15;
    const int lk = l >> 4;
    const int ct = w & 7;
    const int mh = w >> 3;               // rows mh*32 .. mh*32+31

    const __bf16* __restrict__ wr = wt + (size_t)(ct * 16 + lr) * KK + lk * 8;
    const __bf16* a0p = &u.agg[mh * 32 + lr][lk * 8];
    const __bf16* a1p = &u.agg[mh * 32 + 16 + lr][lk * 8];

    f32x4v acc0 = {0.f, 0.f, 0.f, 0.f};
    f32x4v acc1 = {0.f, 0.f, 0.f, 0.f};
    #pragma unroll 4
    for (int k0 = 0; k0 < KR; k0 += 32) {
        const bf16x8 wf = *(const bf16x8*)(wr + k0);     // global b128, L2-hit
        const bf16x8 a0 = *(const bf16x8*)(a0p + k0);    // ds_read_b128
        const bf16x8 a1 = *(const bf16x8*)(a1p + k0);
        acc0 = __builtin_amdgcn_mfma_f32_16x16x32_bf16(a0, wf, acc0, 0, 0, 0);
        acc1 = __builtin_amdgcn_mfma_f32_16x16x32_bf16(a1, wf, acc1, 0, 0, 0);
    }
    {
        const __bf16* __restrict__ sp0 =
            xtb + ((size_t)b * N_ + n0 + mh * 32 + lr) * D_ + lk * 8;
        const __bf16* __restrict__ sp1 = sp0 + 16 * D_;
        #pragma unroll
        for (int k0 = 0; k0 < D_; k0 += 32) {
            const bf16x8 wf = *(const bf16x8*)(wr + KR + k0);
            const bf16x8 a0 = *(const bf16x8*)(sp0 + k0);
            const bf16x8 a1 = *(const bf16x8*)(sp1 + k0);
            acc0 = __builtin_amdgcn_mfma_f32_16x16x32_bf16(a0, wf, acc0, 0, 0, 0);
            acc1 = __builtin_amdgcn_mfma_f32_16x16x32_bf16(a1, wf, acc1, 0, 0, 0);
        }
    }

    const float bv = bias[ct * 16 + lr];
    #pragma unroll
    for (int j = 0; j < 4; ++j) {
        const int row = mh * 32 + lk * 4 + j;
        float* op = out + ((size_t)b * N_ + n0 + row) * O_ + ct * 16 + lr;
        op[0]       = fmaxf(acc0[j] + bv, 0.f);
        op[16 * O_] = fmaxf(acc1[j] + bv, 0.f);
    }
}

extern "C" void kernel_launch(void* const* d_in, const int* in_sizes, int n_in,
                              void* d_out, int out_size, void* d_ws, size_t ws_size,
                              hipStream_t stream) {
    const float* nf    = (const float*)d_in[0];  // node_features  [B,N,D] f32
    const int*   nbr   = (const int*)  d_in[1];  // neighbor_indices [B,R,N,K] i32
    const float* relk  = (const float*)d_in[2];  // relation_kernels [R,D,O] f32
    const float* selfk = (const float*)d_in[3];  // self_kernel [D,O] f32
    const float* bias  = (const float*)d_in[4];  // bias [O] f32
    float* outp = (float*)d_out;                 // [B,N,O] f32

    // ws layout: xtb (bf16) | wt | xt8 (fp8)
    __bf16* xtb = (__bf16*)d_ws;                               // 4,194,304 B
    __bf16* wtp = xtb + (size_t)B_ * N_ * D_;                  // 163,840 B
    unsigned char* xt8 = (unsigned char*)(wtp + (size_t)O_ * KK);  // 2,097,152 B

    {
        const int total = B_ * N_ * (D_ / 4) + O_ * (KK / 4);
        prep_all<<<(total + 255) / 256, 256, 0, stream>>>(nf, relk, selfk,
                                                          xtb, xt8, wtp);
    }

    dim3 grid(B_ * (N_ / TN));                   // 256 blocks, 1 per CU
    gcn_fused<<<grid, THREADS, 0, stream>>>(xtb, xt8, nbr, wtp, bias, outp);
}

// Round 15
// 34.217 us; speedup vs baseline: 1.3909x; 1.3909x over previous
//
#include <hip/hip_runtime.h>
#include <cstddef>

// Problem constants (from reference): B=4, N=4096, D=128, R=4, K=16, O=128
namespace {
constexpr int B_ = 4, N_ = 4096, D_ = 128, R_ = 4, K_ = 16, O_ = 128;
constexpr int NP1 = N_ + 1;            // padded fp8 table rows (row 0 = zeros)
constexpr int TN = 32;                 // nodes per block
constexpr int THREADS = 512;           // 8 waves
constexpr int KK = (R_ + 1) * D_;      // 640 stacked-K (4 relations + self)
constexpr int KR = R_ * D_;            // 512 relation-K (in LDS)
constexpr int PITCH_A = KR + 8;        // 520 bf16 per agg row (self not staged)
}

typedef __bf16 bf16x8 __attribute__((ext_vector_type(8)));
typedef __bf16 bf16x4 __attribute__((ext_vector_type(4)));
typedef float  f32x4v __attribute__((ext_vector_type(4)));
typedef float  f32x2v __attribute__((ext_vector_type(2)));
using u32 = unsigned int;

// ---- prep: fp8 padded table + bf16 W^T (no bf16 table -- self comes from nf) ----
// ptab8 [B][NP1][D] fp8 e4m3 : row 0 zeros, row i+1 = node i features
// wt    [O][KK] bf16         : wt[o][kk] = stackedW[kk][o]
__global__ __launch_bounds__(256)
void prep_all(const float* __restrict__ nf, const float* __restrict__ relk,
              const float* __restrict__ selfk,
              unsigned char* __restrict__ ptab8, __bf16* __restrict__ wt) {
    int t = blockIdx.x * 256 + threadIdx.x;
    const int total_tab = B_ * NP1 * (D_ / 4);          // 4-element chunks
    if (t < total_tab) {
        const int b   = t / (NP1 * 32);
        const int rem = t % (NP1 * 32);
        const int row = rem >> 5;
        const int q   = rem & 31;
        u32 v8 = 0u;
        if (row != 0) {
            const float4 v = *(const float4*)(nf + ((size_t)b * N_ + (row - 1)) * D_ + q * 4);
            v8 = (u32)__builtin_amdgcn_cvt_pk_fp8_f32(v.x, v.y, 0, false);
            v8 = (u32)__builtin_amdgcn_cvt_pk_fp8_f32(v.z, v.w, (int)v8, true);
        }
        *(u32*)(ptab8 + ((size_t)b * NP1 + row) * D_ + q * 4) = v8;
        return;
    }
    t -= total_tab;
    if (t < O_ * (KK / 4)) {
        const int o   = t / (KK / 4);
        const int kk  = (t % (KK / 4)) * 4;
        bf16x4 res;
        #pragma unroll
        for (int i = 0; i < 4; ++i) {
            const int kki = kk + i;
            const float w = (kki < KR) ? relk[(size_t)kki * O_ + o]
                                       : selfk[(size_t)(kki - KR) * O_ + o];
            res[i] = (__bf16)w;
        }
        *(bf16x4*)(wt + (size_t)o * KK + kk) = res;
    }
}

// ---- main: TN=32 fused. fp8 8-rows/inst gather, then MFMA with W reuse ----
// (r12 structure; self-feature fragments built from nf directly)
__global__ __launch_bounds__(THREADS, 4)
void gcn_fused(const unsigned char* __restrict__ ptab8, // [B][NP1][D] fp8
               const int*    __restrict__ nbr,          // [B][R][N][K]
               const __bf16* __restrict__ wt,           // [O][KK] bf16
               const float*  __restrict__ bias,         // [O]
               const float*  __restrict__ nf,           // [B][N][D] f32
               float*        __restrict__ out)          // [B][N][O]
{
    __shared__ __bf16 agg[TN][PITCH_A];          // 32 x 520 bf16 = 33280 B

    // batch<->XCD affinity (r2-verified: FETCH 158 MB -> 6.8 MB)
    const int hw   = blockIdx.x;                 // 512 blocks
    const int xcd  = hw & 7;
    const int b    = xcd >> 1;
    const int tile = (xcd & 1) + ((hw >> 3) << 1);   // 0..127 within batch
    const int n0   = tile * TN;

    const int tid = threadIdx.x;
    const int wv  = tid >> 6;            // 0..7
    const int l   = tid & 63;

    // ---- Phase 1: gather + mean. Wave wv: relation wv&3, nodes
    // {ob..ob+7} and {ob+16..ob+23} (ob = (wv>>2)*8). Lane l owns
    // (node ob+(l>>3)(+16), fp8 chunk (l&7)*16B). One dwordx4 = 8 rows.
    {
        const int r    = wv & 3;
        const int ob   = (wv >> 2) * 8;
        const int nloc = l >> 3;
        const int cch  = l & 7;
        const int ioff = __builtin_amdgcn_readfirstlane(
            (((b * R_ + r) * N_) + n0) * K_);
        const int* __restrict__ ib = nbr + ioff;
        const unsigned char* __restrict__ tb8 = ptab8 + (size_t)b * NP1 * D_;

        const int na  = ob + nloc;           // octet-A node (row in agg)
        const int nb2 = na + 16;             // octet-B node
        const int4 ia0 = *(const int4*)(ib + na  * K_ + 0);
        const int4 ia1 = *(const int4*)(ib + na  * K_ + 4);
        const int4 ia2 = *(const int4*)(ib + na  * K_ + 8);
        const int4 ia3 = *(const int4*)(ib + na  * K_ + 12);
        const int4 ja0 = *(const int4*)(ib + nb2 * K_ + 0);
        const int4 ja1 = *(const int4*)(ib + nb2 * K_ + 4);
        const int4 ja2 = *(const int4*)(ib + nb2 * K_ + 8);
        const int4 ja3 = *(const int4*)(ib + nb2 * K_ + 12);

        f32x2v acc0, acc1, acc2, acc3, acc4, acc5, acc6, acc7;
        constexpr float s = 1.0f / (float)K_;

        #define GCN_ROW(IDX)                                                   \
        {                                                                      \
            const uint4 u = *(const uint4*)(tb8 + (size_t)(IDX) * D_ + cch*16);\
            acc0 += __builtin_amdgcn_cvt_pk_f32_fp8(u.x, false);               \
            acc1 += __builtin_amdgcn_cvt_pk_f32_fp8(u.x, true);                \
            acc2 += __builtin_amdgcn_cvt_pk_f32_fp8(u.y, false);               \
            acc3 += __builtin_amdgcn_cvt_pk_f32_fp8(u.y, true);                \
            acc4 += __builtin_amdgcn_cvt_pk_f32_fp8(u.z, false);               \
            acc5 += __builtin_amdgcn_cvt_pk_f32_fp8(u.z, true);                \
            acc6 += __builtin_amdgcn_cvt_pk_f32_fp8(u.w, false);               \
            acc7 += __builtin_amdgcn_cvt_pk_f32_fp8(u.w, true);                \
        }
        #define GCN_PACK_STORE(ROW)                                            \
        {                                                                      \
            bf16x8 r0, r1;                                                     \
            r0[0] = (__bf16)(acc0.x * s); r0[1] = (__bf16)(acc0.y * s);        \
            r0[2] = (__bf16)(acc1.x * s); r0[3] = (__bf16)(acc1.y * s);        \
            r0[4] = (__bf16)(acc2.x * s); r0[5] = (__bf16)(acc2.y * s);        \
            r0[6] = (__bf16)(acc3.x * s); r0[7] = (__bf16)(acc3.y * s);        \
            r1[0] = (__bf16)(acc4.x * s); r1[1] = (__bf16)(acc4.y * s);        \
            r1[2] = (__bf16)(acc5.x * s); r1[3] = (__bf16)(acc5.y * s);        \
            r1[4] = (__bf16)(acc6.x * s); r1[5] = (__bf16)(acc6.y * s);        \
            r1[6] = (__bf16)(acc7.x * s); r1[7] = (__bf16)(acc7.y * s);        \
            __bf16* dst = &agg[ROW][r * D_ + cch * 16];                        \
            *(bf16x8*)(dst)     = r0;                                          \
            *(bf16x8*)(dst + 8) = r1;                                          \
        }

        acc0 = {0.f,0.f}; acc1 = {0.f,0.f}; acc2 = {0.f,0.f}; acc3 = {0.f,0.f};
        acc4 = {0.f,0.f}; acc5 = {0.f,0.f}; acc6 = {0.f,0.f}; acc7 = {0.f,0.f};
        GCN_ROW(ia0.x) GCN_ROW(ia0.y) GCN_ROW(ia0.z) GCN_ROW(ia0.w)
        GCN_ROW(ia1.x) GCN_ROW(ia1.y) GCN_ROW(ia1.z) GCN_ROW(ia1.w)
        GCN_ROW(ia2.x) GCN_ROW(ia2.y) GCN_ROW(ia2.z) GCN_ROW(ia2.w)
        GCN_ROW(ia3.x) GCN_ROW(ia3.y) GCN_ROW(ia3.z) GCN_ROW(ia3.w)
        GCN_PACK_STORE(na)

        acc0 = {0.f,0.f}; acc1 = {0.f,0.f}; acc2 = {0.f,0.f}; acc3 = {0.f,0.f};
        acc4 = {0.f,0.f}; acc5 = {0.f,0.f}; acc6 = {0.f,0.f}; acc7 = {0.f,0.f};
        GCN_ROW(ja0.x) GCN_ROW(ja0.y) GCN_ROW(ja0.z) GCN_ROW(ja0.w)
        GCN_ROW(ja1.x) GCN_ROW(ja1.y) GCN_ROW(ja1.z) GCN_ROW(ja1.w)
        GCN_ROW(ja2.x) GCN_ROW(ja2.y) GCN_ROW(ja2.z) GCN_ROW(ja2.w)
        GCN_ROW(ja3.x) GCN_ROW(ja3.y) GCN_ROW(ja3.z) GCN_ROW(ja3.w)
        GCN_PACK_STORE(nb2)
        #undef GCN_ROW
        #undef GCN_PACK_STORE
    }
    __syncthreads();

    // ---- Phase 2: MFMA. Wave wv = col-tile wv (16 cols), M=32 as two
    // 16-row blocks. Relation-K (512) from LDS; self-K (128) A-fragments
    // built from f32 nf (L2-hot, identical bf16 conversion), W-self from wt.
    // f32 loads are issued right after the barrier and converted BEFORE the
    // relation loop so the 64 transient f32 VGPRs don't overlap loop
    // pressure (r11 lesson).
    const int lr = l & 15;               // A row / C col index
    const int lk = l >> 4;               // k-group
    const int ct = wv;                   // 0..7

    const __bf16* __restrict__ wr = wt + (size_t)(ct * 16 + lr) * KK + lk * 8;
    const float*  __restrict__ nfr0 = nf + ((size_t)b * N_ + n0 + lr) * D_ + lk * 8;
    const float*  __restrict__ nfr1 = nfr0 + 16 * D_;

    bf16x8 ws0 = *(const bf16x8*)(wr + KR + 0);
    bf16x8 ws1 = *(const bf16x8*)(wr + KR + 32);
    bf16x8 ws2 = *(const bf16x8*)(wr + KR + 64);
    bf16x8 ws3 = *(const bf16x8*)(wr + KR + 96);

    const float4 fa0 = *(const float4*)(nfr0 + 0),   fa0h = *(const float4*)(nfr0 + 4);
    const float4 fa1 = *(const float4*)(nfr0 + 32),  fa1h = *(const float4*)(nfr0 + 36);
    const float4 fa2 = *(const float4*)(nfr0 + 64),  fa2h = *(const float4*)(nfr0 + 68);
    const float4 fa3 = *(const float4*)(nfr0 + 96),  fa3h = *(const float4*)(nfr0 + 100);
    const float4 fb0 = *(const float4*)(nfr1 + 0),   fb0h = *(const float4*)(nfr1 + 4);
    const float4 fb1 = *(const float4*)(nfr1 + 32),  fb1h = *(const float4*)(nfr1 + 36);
    const float4 fb2 = *(const float4*)(nfr1 + 64),  fb2h = *(const float4*)(nfr1 + 68);
    const float4 fb3 = *(const float4*)(nfr1 + 96),  fb3h = *(const float4*)(nfr1 + 100);

    #define CVT8(LO, HI) ({ bf16x8 _r;                                         \
        _r[0]=(__bf16)(LO).x; _r[1]=(__bf16)(LO).y;                            \
        _r[2]=(__bf16)(LO).z; _r[3]=(__bf16)(LO).w;                            \
        _r[4]=(__bf16)(HI).x; _r[5]=(__bf16)(HI).y;                            \
        _r[6]=(__bf16)(HI).z; _r[7]=(__bf16)(HI).w; _r; })
    const bf16x8 sa0 = CVT8(fa0, fa0h), sa1 = CVT8(fa1, fa1h);
    const bf16x8 sa2 = CVT8(fa2, fa2h), sa3 = CVT8(fa3, fa3h);
    const bf16x8 sb0 = CVT8(fb0, fb0h), sb1 = CVT8(fb1, fb1h);
    const bf16x8 sb2 = CVT8(fb2, fb2h), sb3 = CVT8(fb3, fb3h);
    #undef CVT8

    const __bf16* a0p = &agg[lr][lk * 8];
    const __bf16* a1p = &agg[lr + 16][lk * 8];

    f32x4v acc0 = {0.f, 0.f, 0.f, 0.f};
    f32x4v acc1 = {0.f, 0.f, 0.f, 0.f};
    #pragma unroll 4
    for (int k0 = 0; k0 < KR; k0 += 32) {
        const bf16x8 w  = *(const bf16x8*)(wr + k0);     // global b128, L2-hit
        const bf16x8 a0 = *(const bf16x8*)(a0p + k0);    // ds_read_b128
        const bf16x8 a1 = *(const bf16x8*)(a1p + k0);
        acc0 = __builtin_amdgcn_mfma_f32_16x16x32_bf16(a0, w, acc0, 0, 0, 0);
        acc1 = __builtin_amdgcn_mfma_f32_16x16x32_bf16(a1, w, acc1, 0, 0, 0);
    }
    // self-K from the preconverted registers
    acc0 = __builtin_amdgcn_mfma_f32_16x16x32_bf16(sa0, ws0, acc0, 0, 0, 0);
    acc1 = __builtin_amdgcn_mfma_f32_16x16x32_bf16(sb0, ws0, acc1, 0, 0, 0);
    acc0 = __builtin_amdgcn_mfma_f32_16x16x32_bf16(sa1, ws1, acc0, 0, 0, 0);
    acc1 = __builtin_amdgcn_mfma_f32_16x16x32_bf16(sb1, ws1, acc1, 0, 0, 0);
    acc0 = __builtin_amdgcn_mfma_f32_16x16x32_bf16(sa2, ws2, acc0, 0, 0, 0);
    acc1 = __builtin_amdgcn_mfma_f32_16x16x32_bf16(sb2, ws2, acc1, 0, 0, 0);
    acc0 = __builtin_amdgcn_mfma_f32_16x16x32_bf16(sa3, ws3, acc0, 0, 0, 0);
    acc1 = __builtin_amdgcn_mfma_f32_16x16x32_bf16(sb3, ws3, acc1, 0, 0, 0);

    const float bv = bias[ct * 16 + lr];
    #pragma unroll
    for (int j = 0; j < 4; ++j) {
        const int row = lk * 4 + j;      // node within 16-row block
        float* op = out + ((size_t)b * N_ + n0 + row) * O_ + ct * 16 + lr;
        op[0]        = fmaxf(acc0[j] + bv, 0.f);
        op[16 * O_]  = fmaxf(acc1[j] + bv, 0.f);
    }
}

extern "C" void kernel_launch(void* const* d_in, const int* in_sizes, int n_in,
                              void* d_out, int out_size, void* d_ws, size_t ws_size,
                              hipStream_t stream) {
    const float* nf    = (const float*)d_in[0];  // node_features  [B,N,D] f32
    const int*   nbr   = (const int*)  d_in[1];  // neighbor_indices [B,R,N,K] i32
    const float* relk  = (const float*)d_in[2];  // relation_kernels [R,D,O] f32
    const float* selfk = (const float*)d_in[3];  // self_kernel [D,O] f32
    const float* bias  = (const float*)d_in[4];  // bias [O] f32
    float* outp = (float*)d_out;                 // [B,N,O] f32

    // ws layout: ptab8 (fp8) | wt
    unsigned char* ptab8 = (unsigned char*)d_ws;               // 2,097,664 B
    __bf16* wtp = (__bf16*)(ptab8 + (size_t)B_ * NP1 * D_);    // 163,840 B

    {
        const int total = B_ * NP1 * (D_ / 4) + O_ * (KK / 4);
        prep_all<<<(total + 255) / 256, 256, 0, stream>>>(nf, relk, selfk,
                                                          ptab8, wtp);
    }

    dim3 grid(B_ * (N_ / TN));
    gcn_fused<<<grid, THREADS, 0, stream>>>(ptab8, nbr, wtp, bias, nf, outp);
}

// Round 16
// 31.752 us; speedup vs baseline: 1.4989x; 1.0776x over previous
//
#include <hip/hip_runtime.h>
#include <cstddef>

// Problem constants (from reference): B=4, N=4096, D=128, R=4, K=16, O=128
namespace {
constexpr int B_ = 4, N_ = 4096, D_ = 128, R_ = 4, K_ = 16, O_ = 128;
constexpr int NP1 = N_ + 1;            // padded table rows (row 0 = zeros)
constexpr int TN = 32;                 // nodes per block
constexpr int THREADS = 512;           // 8 waves
constexpr int KK = (R_ + 1) * D_;      // 640 stacked-K (4 relations + self)
constexpr int KR = R_ * D_;            // 512 relation-K (in LDS)
constexpr int PITCH_A = KR + 8;        // 520 bf16 per agg row (self not staged)
}

typedef __bf16 bf16x8 __attribute__((ext_vector_type(8)));
typedef __bf16 bf16x4 __attribute__((ext_vector_type(4)));
typedef float  f32x4v __attribute__((ext_vector_type(4)));
typedef float  f32x2v __attribute__((ext_vector_type(2)));
using u32 = unsigned int;

// ---- prep (single pass over nf): bf16 + fp8 padded tables + bf16 W^T ----
// ptab  [B][NP1][D] bf16 : row 0 zeros, row i+1 = node i features (self path)
// ptab8 [B][NP1][D] fp8  : same content, e4m3 (gather path, 128 B rows)
// wt    [O][KK] bf16     : wt[o][kk] = stackedW[kk][o]
__global__ __launch_bounds__(256)
void prep_all(const float* __restrict__ nf, const float* __restrict__ relk,
              const float* __restrict__ selfk,
              __bf16* __restrict__ ptab, unsigned char* __restrict__ ptab8,
              __bf16* __restrict__ wt) {
    int t = blockIdx.x * 256 + threadIdx.x;
    const int total_tab = B_ * NP1 * (D_ / 4);          // 4-element chunks
    if (t < total_tab) {
        const int b   = t / (NP1 * 32);
        const int rem = t % (NP1 * 32);
        const int row = rem >> 5;
        const int q   = rem & 31;
        bf16x4 res;
        u32 v8 = 0u;
        if (row == 0) {
            res[0] = (__bf16)0.f; res[1] = (__bf16)0.f;
            res[2] = (__bf16)0.f; res[3] = (__bf16)0.f;
        } else {
            const float4 v = *(const float4*)(nf + ((size_t)b * N_ + (row - 1)) * D_ + q * 4);
            res[0] = (__bf16)v.x; res[1] = (__bf16)v.y;
            res[2] = (__bf16)v.z; res[3] = (__bf16)v.w;
            v8 = (u32)__builtin_amdgcn_cvt_pk_fp8_f32(v.x, v.y, 0, false);
            v8 = (u32)__builtin_amdgcn_cvt_pk_fp8_f32(v.z, v.w, (int)v8, true);
        }
        *(bf16x4*)(ptab + ((size_t)b * NP1 + row) * D_ + q * 4) = res;
        *(u32*)(ptab8 + ((size_t)b * NP1 + row) * D_ + q * 4) = v8;
        return;
    }
    t -= total_tab;
    if (t < O_ * (KK / 4)) {
        const int o   = t / (KK / 4);
        const int kk  = (t % (KK / 4)) * 4;
        bf16x4 res;
        #pragma unroll
        for (int i = 0; i < 4; ++i) {
            const int kki = kk + i;
            const float w = (kki < KR) ? relk[(size_t)kki * O_ + o]
                                       : selfk[(size_t)(kki - KR) * O_ + o];
            res[i] = (__bf16)w;
        }
        *(bf16x4*)(wt + (size_t)o * KK + kk) = res;
    }
}

// ---- main: TN=32 fused. fp8 8-rows/inst gather, then MFMA with W reuse ----
// (r10 structure; phase-2 self/W-self loads issued early after the barrier)
__global__ __launch_bounds__(THREADS, 4)
void gcn_fused(const __bf16* __restrict__ ptab,         // [B][NP1][D] bf16
               const unsigned char* __restrict__ ptab8, // [B][NP1][D] fp8
               const int*    __restrict__ nbr,          // [B][R][N][K]
               const __bf16* __restrict__ wt,           // [O][KK] bf16
               const float*  __restrict__ bias,         // [O]
               float*        __restrict__ out)          // [B][N][O]
{
    __shared__ __bf16 agg[TN][PITCH_A];          // 32 x 520 bf16 = 33280 B

    // batch<->XCD affinity (r2-verified: FETCH 158 MB -> 6.8 MB)
    const int hw   = blockIdx.x;                 // 512 blocks
    const int xcd  = hw & 7;
    const int b    = xcd >> 1;
    const int tile = (xcd & 1) + ((hw >> 3) << 1);   // 0..127 within batch
    const int n0   = tile * TN;

    const int tid = threadIdx.x;
    const int wv  = tid >> 6;            // 0..7
    const int l   = tid & 63;

    // ---- Phase 1: gather + mean. Wave wv: relation wv&3, nodes
    // {ob..ob+7} and {ob+16..ob+23} (ob = (wv>>2)*8). Lane l owns
    // (node ob+(l>>3)(+16), fp8 chunk (l&7)*16B). One dwordx4 = 8 rows.
    {
        const int r    = wv & 3;
        const int ob   = (wv >> 2) * 8;
        const int nloc = l >> 3;
        const int cch  = l & 7;
        const int ioff = __builtin_amdgcn_readfirstlane(
            (((b * R_ + r) * N_) + n0) * K_);
        const int* __restrict__ ib = nbr + ioff;
        const unsigned char* __restrict__ tb8 = ptab8 + (size_t)b * NP1 * D_;

        const int na  = ob + nloc;           // octet-A node (row in agg)
        const int nb2 = na + 16;             // octet-B node
        const int4 ia0 = *(const int4*)(ib + na  * K_ + 0);
        const int4 ia1 = *(const int4*)(ib + na  * K_ + 4);
        const int4 ia2 = *(const int4*)(ib + na  * K_ + 8);
        const int4 ia3 = *(const int4*)(ib + na  * K_ + 12);
        const int4 ja0 = *(const int4*)(ib + nb2 * K_ + 0);
        const int4 ja1 = *(const int4*)(ib + nb2 * K_ + 4);
        const int4 ja2 = *(const int4*)(ib + nb2 * K_ + 8);
        const int4 ja3 = *(const int4*)(ib + nb2 * K_ + 12);

        f32x2v acc0, acc1, acc2, acc3, acc4, acc5, acc6, acc7;
        constexpr float s = 1.0f / (float)K_;

        #define GCN_ROW(IDX)                                                   \
        {                                                                      \
            const uint4 u = *(const uint4*)(tb8 + (size_t)(IDX) * D_ + cch*16);\
            acc0 += __builtin_amdgcn_cvt_pk_f32_fp8(u.x, false);               \
            acc1 += __builtin_amdgcn_cvt_pk_f32_fp8(u.x, true);                \
            acc2 += __builtin_amdgcn_cvt_pk_f32_fp8(u.y, false);               \
            acc3 += __builtin_amdgcn_cvt_pk_f32_fp8(u.y, true);                \
            acc4 += __builtin_amdgcn_cvt_pk_f32_fp8(u.z, false);               \
            acc5 += __builtin_amdgcn_cvt_pk_f32_fp8(u.z, true);                \
            acc6 += __builtin_amdgcn_cvt_pk_f32_fp8(u.w, false);               \
            acc7 += __builtin_amdgcn_cvt_pk_f32_fp8(u.w, true);                \
        }
        #define GCN_PACK_STORE(ROW)                                            \
        {                                                                      \
            bf16x8 r0, r1;                                                     \
            r0[0] = (__bf16)(acc0.x * s); r0[1] = (__bf16)(acc0.y * s);        \
            r0[2] = (__bf16)(acc1.x * s); r0[3] = (__bf16)(acc1.y * s);        \
            r0[4] = (__bf16)(acc2.x * s); r0[5] = (__bf16)(acc2.y * s);        \
            r0[6] = (__bf16)(acc3.x * s); r0[7] = (__bf16)(acc3.y * s);        \
            r1[0] = (__bf16)(acc4.x * s); r1[1] = (__bf16)(acc4.y * s);        \
            r1[2] = (__bf16)(acc5.x * s); r1[3] = (__bf16)(acc5.y * s);        \
            r1[4] = (__bf16)(acc6.x * s); r1[5] = (__bf16)(acc6.y * s);        \
            r1[6] = (__bf16)(acc7.x * s); r1[7] = (__bf16)(acc7.y * s);        \
            __bf16* dst = &agg[ROW][r * D_ + cch * 16];                        \
            *(bf16x8*)(dst)     = r0;                                          \
            *(bf16x8*)(dst + 8) = r1;                                          \
        }

        acc0 = {0.f,0.f}; acc1 = {0.f,0.f}; acc2 = {0.f,0.f}; acc3 = {0.f,0.f};
        acc4 = {0.f,0.f}; acc5 = {0.f,0.f}; acc6 = {0.f,0.f}; acc7 = {0.f,0.f};
        GCN_ROW(ia0.x) GCN_ROW(ia0.y) GCN_ROW(ia0.z) GCN_ROW(ia0.w)
        GCN_ROW(ia1.x) GCN_ROW(ia1.y) GCN_ROW(ia1.z) GCN_ROW(ia1.w)
        GCN_ROW(ia2.x) GCN_ROW(ia2.y) GCN_ROW(ia2.z) GCN_ROW(ia2.w)
        GCN_ROW(ia3.x) GCN_ROW(ia3.y) GCN_ROW(ia3.z) GCN_ROW(ia3.w)
        GCN_PACK_STORE(na)

        acc0 = {0.f,0.f}; acc1 = {0.f,0.f}; acc2 = {0.f,0.f}; acc3 = {0.f,0.f};
        acc4 = {0.f,0.f}; acc5 = {0.f,0.f}; acc6 = {0.f,0.f}; acc7 = {0.f,0.f};
        GCN_ROW(ja0.x) GCN_ROW(ja0.y) GCN_ROW(ja0.z) GCN_ROW(ja0.w)
        GCN_ROW(ja1.x) GCN_ROW(ja1.y) GCN_ROW(ja1.z) GCN_ROW(ja1.w)
        GCN_ROW(ja2.x) GCN_ROW(ja2.y) GCN_ROW(ja2.z) GCN_ROW(ja2.w)
        GCN_ROW(ja3.x) GCN_ROW(ja3.y) GCN_ROW(ja3.z) GCN_ROW(ja3.w)
        GCN_PACK_STORE(nb2)
        #undef GCN_ROW
        #undef GCN_PACK_STORE
    }
    __syncthreads();

    // ---- Phase 2: MFMA. Wave wv = col-tile wv (16 cols), M=32 as two
    // 16-row blocks. Relation-K (512) from LDS; self-K (128) + its W from
    // global. The 12 global loads are ISSUED FIRST (right after the
    // barrier) so their L2 latency drains under the 16-step LDS MFMA loop.
    // These 48 dest VGPRs are live only in phase 2 (gather regs dead) --
    // no cross-phase pressure (r11 lesson).
    const int lr = l & 15;               // A row / C col index
    const int lk = l >> 4;               // k-group
    const int ct = wv;                   // 0..7

    const __bf16* __restrict__ wr = wt + (size_t)(ct * 16 + lr) * KK + lk * 8;
    const __bf16* __restrict__ sp0 =
        ptab + ((size_t)b * NP1 + n0 + lr + 1) * D_ + lk * 8;
    const __bf16* __restrict__ sp1 = sp0 + 16 * D_;

    // issue-early: self A-fragments + self-W fragments
    bf16x8 ws0 = *(const bf16x8*)(wr + KR + 0);
    bf16x8 ws1 = *(const bf16x8*)(wr + KR + 32);
    bf16x8 ws2 = *(const bf16x8*)(wr + KR + 64);
    bf16x8 ws3 = *(const bf16x8*)(wr + KR + 96);
    bf16x8 sa0 = *(const bf16x8*)(sp0 + 0);
    bf16x8 sa1 = *(const bf16x8*)(sp0 + 32);
    bf16x8 sa2 = *(const bf16x8*)(sp0 + 64);
    bf16x8 sa3 = *(const bf16x8*)(sp0 + 96);
    bf16x8 sb0 = *(const bf16x8*)(sp1 + 0);
    bf16x8 sb1 = *(const bf16x8*)(sp1 + 32);
    bf16x8 sb2 = *(const bf16x8*)(sp1 + 64);
    bf16x8 sb3 = *(const bf16x8*)(sp1 + 96);

    const __bf16* a0p = &agg[lr][lk * 8];
    const __bf16* a1p = &agg[lr + 16][lk * 8];

    f32x4v acc0 = {0.f, 0.f, 0.f, 0.f};
    f32x4v acc1 = {0.f, 0.f, 0.f, 0.f};
    #pragma unroll 4
    for (int k0 = 0; k0 < KR; k0 += 32) {
        const bf16x8 w  = *(const bf16x8*)(wr + k0);     // global b128, L2-hit
        const bf16x8 a0 = *(const bf16x8*)(a0p + k0);    // ds_read_b128
        const bf16x8 a1 = *(const bf16x8*)(a1p + k0);
        acc0 = __builtin_amdgcn_mfma_f32_16x16x32_bf16(a0, w, acc0, 0, 0, 0);
        acc1 = __builtin_amdgcn_mfma_f32_16x16x32_bf16(a1, w, acc1, 0, 0, 0);
    }
    // self-K from the preloaded registers
    acc0 = __builtin_amdgcn_mfma_f32_16x16x32_bf16(sa0, ws0, acc0, 0, 0, 0);
    acc1 = __builtin_amdgcn_mfma_f32_16x16x32_bf16(sb0, ws0, acc1, 0, 0, 0);
    acc0 = __builtin_amdgcn_mfma_f32_16x16x32_bf16(sa1, ws1, acc0, 0, 0, 0);
    acc1 = __builtin_amdgcn_mfma_f32_16x16x32_bf16(sb1, ws1, acc1, 0, 0, 0);
    acc0 = __builtin_amdgcn_mfma_f32_16x16x32_bf16(sa2, ws2, acc0, 0, 0, 0);
    acc1 = __builtin_amdgcn_mfma_f32_16x16x32_bf16(sb2, ws2, acc1, 0, 0, 0);
    acc0 = __builtin_amdgcn_mfma_f32_16x16x32_bf16(sa3, ws3, acc0, 0, 0, 0);
    acc1 = __builtin_amdgcn_mfma_f32_16x16x32_bf16(sb3, ws3, acc1, 0, 0, 0);

    const float bv = bias[ct * 16 + lr];
    #pragma unroll
    for (int j = 0; j < 4; ++j) {
        const int row = lk * 4 + j;      // node within 16-row block
        float* op = out + ((size_t)b * N_ + n0 + row) * O_ + ct * 16 + lr;
        op[0]        = fmaxf(acc0[j] + bv, 0.f);
        op[16 * O_]  = fmaxf(acc1[j] + bv, 0.f);
    }
}

extern "C" void kernel_launch(void* const* d_in, const int* in_sizes, int n_in,
                              void* d_out, int out_size, void* d_ws, size_t ws_size,
                              hipStream_t stream) {
    const float* nf    = (const float*)d_in[0];  // node_features  [B,N,D] f32
    const int*   nbr   = (const int*)  d_in[1];  // neighbor_indices [B,R,N,K] i32
    const float* relk  = (const float*)d_in[2];  // relation_kernels [R,D,O] f32
    const float* selfk = (const float*)d_in[3];  // self_kernel [D,O] f32
    const float* bias  = (const float*)d_in[4];  // bias [O] f32
    float* outp = (float*)d_out;                 // [B,N,O] f32

    // ws layout: ptab (bf16) | wt | ptab8 (fp8)
    __bf16* ptab = (__bf16*)d_ws;                              // 4,195,328 B
    __bf16* wtp  = ptab + (size_t)B_ * NP1 * D_;               // 163,840 B
    unsigned char* ptab8 = (unsigned char*)(wtp + (size_t)O_ * KK);  // 2,097,664 B

    {
        const int total = B_ * NP1 * (D_ / 4) + O_ * (KK / 4);
        prep_all<<<(total + 255) / 256, 256, 0, stream>>>(nf, relk, selfk,
                                                          ptab, ptab8, wtp);
    }

    dim3 grid(B_ * (N_ / TN));
    gcn_fused<<<grid, THREADS, 0, stream>>>(ptab, ptab8, nbr, wtp, bias, outp);
}